// Round 2
// baseline (827.457 us; speedup 1.0000x reference)
//
#include <hip/hip_runtime.h>
#include <hip/hip_cooperative_groups.h>
#include <math.h>

namespace cg = cooperative_groups;

// Problem constants (B,T,D) = (32, 2048, 512), fp32.
constexpr int B = 32;
constexpr int T = 2048;
constexpr int D = 512;

constexpr int NBLK = 1024;                     // 4 blocks/CU on 256 CUs -> co-resident
constexpr int NTHR = 256;                      // 4 waves
constexpr int ROWS_PER_BLK = (B * T) / NBLK;   // 64 rows (t values) per block
constexpr int BLKS_PER_B = T / ROWS_PER_BLK;   // 32 blocks per batch

__global__ __launch_bounds__(NTHR, 4)
void fused_kernel(const float* __restrict__ x, float* __restrict__ out,
                  float* __restrict__ s, float* __restrict__ w,
                  float* __restrict__ Mb, float* __restrict__ Sb)
{
    cg::grid_group grid = cg::this_grid();
    const int g   = blockIdx.x;
    const int tid = threadIdx.x;
    const int b   = g / BLKS_PER_B;                      // batch this block serves
    const int t0  = (g % BLKS_PER_B) * ROWS_PER_BLK;     // first row (t) of its slice
    const float* xb = x + ((size_t)b * T + t0) * D;      // block's x slice [64 x 512]

    __shared__ float red[4];

    // ---------------- P0: zero s[B*D] and out[B*D] ----------------
    {
        int i = g * NTHR + tid;
        if (i < B * D)          s[i] = 0.0f;
        else if (i < 2 * B * D) out[i - B * D] = 0.0f;
    }
    __threadfence();
    grid.sync();

    // ---------------- P1: s[b,d] += sum over block's 64 rows ----------------
    // thread -> (row parity rp, float4 column d4); block covers 2 full rows/iter (4 KB)
    {
        const int d4 = tid & 127;          // 0..127 -> d = 4*d4
        const int rp = tid >> 7;           // 0 or 1
        const float4* xr = (const float4*)xb + (size_t)rp * (D / 4) + d4;
        float4 acc = make_float4(0.f, 0.f, 0.f, 0.f);
        #pragma unroll 4
        for (int i = 0; i < ROWS_PER_BLK / 2; ++i) {
            float4 v = xr[(size_t)i * (D / 2)];
            acc.x += v.x; acc.y += v.y; acc.z += v.z; acc.w += v.w;
        }
        float* sp = s + (size_t)b * D + d4 * 4;
        atomicAdd(sp + 0, acc.x);
        atomicAdd(sp + 1, acc.y);
        atomicAdd(sp + 2, acc.z);
        atomicAdd(sp + 3, acc.w);
    }
    grid.sync();

    // ---------------- P2: w[b,t] = x_bt . (s_b - x_bt), wave per row ----------------
    {
        const int wid = tid >> 6, lane = tid & 63;
        const float4* sp4 = (const float4*)(s + (size_t)b * D) + lane * 2;
        float4 s0 = sp4[0], s1 = sp4[1];
        for (int i = 0; i < ROWS_PER_BLK / 4; ++i) {     // 16 rows per wave
            const int r = wid * (ROWS_PER_BLK / 4) + i;
            const float4* xp = (const float4*)(xb + (size_t)r * D) + lane * 2;
            float4 x0 = xp[0], x1 = xp[1];
            double acc = 0.0;
            acc += (double)x0.x * (double)(s0.x - x0.x);
            acc += (double)x0.y * (double)(s0.y - x0.y);
            acc += (double)x0.z * (double)(s0.z - x0.z);
            acc += (double)x0.w * (double)(s0.w - x0.w);
            acc += (double)x1.x * (double)(s1.x - x1.x);
            acc += (double)x1.y * (double)(s1.y - x1.y);
            acc += (double)x1.z * (double)(s1.z - x1.z);
            acc += (double)x1.w * (double)(s1.w - x1.w);
            #pragma unroll
            for (int off = 32; off > 0; off >>= 1)
                acc += __shfl_down(acc, off, 64);
            if (lane == 0) w[(size_t)b * T + t0 + r] = (float)acc;
        }
    }
    __threadfence();
    grid.sync();

    // ---------------- P3: per-batch M = max_t w, S = sum exp(w-M); blocks 0..B-1 ----------------
    if (g < B) {
        const float* wb = w + (size_t)g * T;
        float v[T / NTHR];                               // 8 values/thread
        float m = -INFINITY;
        #pragma unroll
        for (int k = 0; k < T / NTHR; ++k) {
            v[k] = wb[tid + k * NTHR];
            m = fmaxf(m, v[k]);
        }
        #pragma unroll
        for (int off = 32; off > 0; off >>= 1) m = fmaxf(m, __shfl_down(m, off, 64));
        if ((tid & 63) == 0) red[tid >> 6] = m;
        __syncthreads();
        const float M = fmaxf(fmaxf(red[0], red[1]), fmaxf(red[2], red[3]));
        __syncthreads();
        float lsum = 0.f;
        #pragma unroll
        for (int k = 0; k < T / NTHR; ++k) lsum += __expf(v[k] - M);
        #pragma unroll
        for (int off = 32; off > 0; off >>= 1) lsum += __shfl_down(lsum, off, 64);
        if ((tid & 63) == 0) red[tid >> 6] = lsum;
        __syncthreads();
        if (tid == 0) { Mb[g] = M; Sb[g] = red[0] + red[1] + red[2] + red[3]; }
    }
    __threadfence();
    grid.sync();

    // ---------------- P4: out[b,d] += sum over block's rows of exp(w-M)/S * x ----------------
    {
        const float M    = Mb[b];
        const float invS = 1.0f / Sb[b];
        const int d4 = tid & 127;
        const int rp = tid >> 7;
        const float* wrow = w + (size_t)b * T + t0;
        const float4* xr = (const float4*)xb + (size_t)rp * (D / 4) + d4;
        float4 acc = make_float4(0.f, 0.f, 0.f, 0.f);
        #pragma unroll 4
        for (int i = 0; i < ROWS_PER_BLK / 2; ++i) {
            const float wt = __expf(wrow[i * 2 + rp] - M) * invS;
            float4 v = xr[(size_t)i * (D / 2)];
            acc.x += wt * v.x; acc.y += wt * v.y; acc.z += wt * v.z; acc.w += wt * v.w;
        }
        float* op = out + (size_t)b * D + d4 * 4;
        atomicAdd(op + 0, acc.x);
        atomicAdd(op + 1, acc.y);
        atomicAdd(op + 2, acc.z);
        atomicAdd(op + 3, acc.w);
    }
}

extern "C" void kernel_launch(void* const* d_in, const int* in_sizes, int n_in,
                              void* d_out, int out_size, void* d_ws, size_t ws_size,
                              hipStream_t stream) {
    const float* x = (const float*)d_in[0];
    float* out = (float*)d_out;
    float* s  = (float*)d_ws;          // B*D floats
    float* w  = s + B * D;             // B*T floats
    float* Mb = w + B * T;             // B floats
    float* Sb = Mb + B;                // B floats

    void* args[] = { (void*)&x, (void*)&out, (void*)&s, (void*)&w, (void*)&Mb, (void*)&Sb };
    hipLaunchCooperativeKernel((void*)fused_kernel, dim3(NBLK), dim3(NTHR),
                               args, 0, stream);
}

// Round 3
// 229.431 us; speedup vs baseline: 3.6066x; 3.6066x over previous
//
#include <hip/hip_runtime.h>
#include <math.h>

// (B,T,D) = (32, 2048, 512), fp32 in, fp32 out.
constexpr int B = 32;
constexpr int T = 2048;
constexpr int D = 512;

constexpr int C1 = 16;            // K1: chunks over T
constexpr int R1 = T / C1;        // 128 rows per K1 block
constexpr int C2 = 32;            // K2: blocks per batch
constexpr int R2 = T / C2;        // 64 rows per K2 block (16 per wave)
constexpr int NPART = C2 * 4;     // 128 wave-partials per batch

// ---------------- K1: partial column sums, no atomics ----------------
// P1[b][c][d] = sum_{t in chunk c} x[b][t][d]
__global__ __launch_bounds__(256) void colsum_part(const float* __restrict__ x,
                                                   float* __restrict__ P1) {
    const int b = blockIdx.x, c = blockIdx.y;
    const int d4 = threadIdx.x & 127;      // float4 column
    const int rp = threadIdx.x >> 7;       // row parity
    const float4* xp = (const float4*)x + ((size_t)(b * T + c * R1) * D >> 2)
                       + (size_t)rp * (D / 4) + d4;
    float4 acc = {0.f, 0.f, 0.f, 0.f};
    #pragma unroll 8
    for (int i = 0; i < R1 / 2; ++i) {
        float4 v = xp[(size_t)i * (D / 2)];
        acc.x += v.x; acc.y += v.y; acc.z += v.z; acc.w += v.w;
    }
    __shared__ float4 lds[128];
    if (rp == 1) lds[d4] = acc;
    __syncthreads();
    if (rp == 0) {
        float4 o = lds[d4];
        acc.x += o.x; acc.y += o.y; acc.z += o.z; acc.w += o.w;
        ((float4*)P1)[(size_t)(b * C1 + c) * (D / 4) + d4] = acc;
    }
}

// ---------------- K2: fused rowdot + online softmax + pool ----------------
// One wave per 16 rows. Lane owns 8 contiguous columns. Emits per-wave
// partial (M, S, O[512]) — merged in K3. No atomics, no zero-init.
__global__ __launch_bounds__(256) void online_pool(const float* __restrict__ x,
                                                   const float* __restrict__ P1,
                                                   float* __restrict__ Mp,
                                                   float* __restrict__ Sp,
                                                   float* __restrict__ Op) {
    const int b = blockIdx.x, c = blockIdx.y;
    const int wid = threadIdx.x >> 6, lane = threadIdx.x & 63;

    // s at lane's 8 columns = sum of 16 chunk partials
    float4 s0 = {0.f,0.f,0.f,0.f}, s1 = {0.f,0.f,0.f,0.f};
    const float4* pp = (const float4*)P1 + (size_t)b * C1 * (D / 4) + lane * 2;
    #pragma unroll
    for (int k = 0; k < C1; ++k) {
        float4 a = pp[k * (D / 4)], q = pp[k * (D / 4) + 1];
        s0.x += a.x; s0.y += a.y; s0.z += a.z; s0.w += a.w;
        s1.x += q.x; s1.y += q.y; s1.z += q.z; s1.w += q.w;
    }

    float m = -INFINITY, ssum = 0.f;
    float4 O0 = {0.f,0.f,0.f,0.f}, O1 = {0.f,0.f,0.f,0.f};
    const int t0 = c * R2 + wid * (R2 / 4);
    const float4* xr = (const float4*)x + ((size_t)(b * T + t0) * D >> 2) + lane * 2;

    #pragma unroll 2
    for (int i = 0; i < R2 / 4; ++i) {
        float4 x0 = xr[0], x1 = xr[1];
        xr += D / 4;
        double a = 0.0;
        a += (double)x0.x * ((double)s0.x - (double)x0.x);
        a += (double)x0.y * ((double)s0.y - (double)x0.y);
        a += (double)x0.z * ((double)s0.z - (double)x0.z);
        a += (double)x0.w * ((double)s0.w - (double)x0.w);
        a += (double)x1.x * ((double)s1.x - (double)x1.x);
        a += (double)x1.y * ((double)s1.y - (double)x1.y);
        a += (double)x1.z * ((double)s1.z - (double)x1.z);
        a += (double)x1.w * ((double)s1.w - (double)x1.w);
        #pragma unroll
        for (int off = 1; off < 64; off <<= 1)
            a += __shfl_xor(a, off, 64);
        const float wr = (float)a;                // identical on all lanes
        if (wr <= m) {                            // wave-uniform branch
            const float e = __expf(wr - m);
            ssum += e;
            O0.x += e * x0.x; O0.y += e * x0.y; O0.z += e * x0.z; O0.w += e * x0.w;
            O1.x += e * x1.x; O1.y += e * x1.y; O1.z += e * x1.z; O1.w += e * x1.w;
        } else {
            const float al = __expf(m - wr);      // exp(-inf)=0 handles first iter
            ssum = ssum * al + 1.f;
            O0.x = O0.x * al + x0.x; O0.y = O0.y * al + x0.y;
            O0.z = O0.z * al + x0.z; O0.w = O0.w * al + x0.w;
            O1.x = O1.x * al + x1.x; O1.y = O1.y * al + x1.y;
            O1.z = O1.z * al + x1.z; O1.w = O1.w * al + x1.w;
            m = wr;
        }
    }

    const int pi = (b * C2 + c) * 4 + wid;        // partial index: b*128 + ...
    if (lane == 0) { Mp[pi] = m; Sp[pi] = ssum; }
    float4* op = (float4*)Op + (size_t)pi * (D / 4) + lane * 2;
    op[0] = O0; op[1] = O1;
}

// ---------------- K3: merge 128 partials per batch ----------------
__global__ __launch_bounds__(128) void finalize(const float* __restrict__ Mp,
                                                const float* __restrict__ Sp,
                                                const float* __restrict__ Op,
                                                float* __restrict__ out) {
    const int b = blockIdx.x, tid = threadIdx.x;  // 128 threads = 2 waves
    const int wid = tid >> 6;
    __shared__ float fsh[NPART];
    __shared__ float red[2];

    const float Mc = Mp[b * NPART + tid];
    float m = Mc;
    #pragma unroll
    for (int off = 1; off < 64; off <<= 1) m = fmaxf(m, __shfl_xor(m, off, 64));
    if ((tid & 63) == 0) red[wid] = m;
    __syncthreads();
    const float Mg = fmaxf(red[0], red[1]);
    __syncthreads();

    const float f = __expf(Mc - Mg);
    fsh[tid] = f;
    float sp = Sp[b * NPART + tid] * f;
    #pragma unroll
    for (int off = 1; off < 64; off <<= 1) sp += __shfl_xor(sp, off, 64);
    if ((tid & 63) == 0) red[wid] = sp;
    __syncthreads();
    const float Sg = red[0] + red[1];

    float4 acc = {0.f,0.f,0.f,0.f};
    const float4* op = (const float4*)Op + (size_t)b * NPART * (D / 4) + tid;
    #pragma unroll 4
    for (int c = 0; c < NPART; ++c) {
        const float fc = fsh[c];
        float4 v = op[(size_t)c * (D / 4)];
        acc.x += fc * v.x; acc.y += fc * v.y; acc.z += fc * v.z; acc.w += fc * v.w;
    }
    const float inv = 1.0f / Sg;
    acc.x *= inv; acc.y *= inv; acc.z *= inv; acc.w *= inv;
    ((float4*)out)[(size_t)b * (D / 4) + tid] = acc;
}

extern "C" void kernel_launch(void* const* d_in, const int* in_sizes, int n_in,
                              void* d_out, int out_size, void* d_ws, size_t ws_size,
                              hipStream_t stream) {
    const float* x = (const float*)d_in[0];
    float* out = (float*)d_out;

    float* P1 = (float*)d_ws;                 // B*C1*D  = 1 MB
    float* Mp = P1 + (size_t)B * C1 * D;      // B*NPART = 16 KB
    float* Sp = Mp + (size_t)B * NPART;       // B*NPART = 16 KB
    float* Op = Sp + (size_t)B * NPART;       // B*NPART*D = 8 MB

    colsum_part<<<dim3(B, C1), 256, 0, stream>>>(x, P1);
    online_pool<<<dim3(B, C2), 256, 0, stream>>>(x, P1, Mp, Sp, Op);
    finalize<<<B, 128, 0, stream>>>(Mp, Sp, Op, out);
}